// Round 3
// baseline (625.331 us; speedup 1.0000x reference)
//
#include <hip/hip_runtime.h>
#include <math.h>

#define NB 8
#define NC 128
#define NP 96
#define ND 128
#define NH 8
#define NR 16

// XOR swizzle of 16B slots within a 128-float (32-slot) row: permutes bank
// groups by row so strided "column" reads degrade to <=4-way conflicts and
// lane-consecutive reads stay conflict-free.
__device__ __forceinline__ int swz(int s, int row) { return (s & 24) | ((s ^ row) & 7); }

// ---------------- time-message kernel: one block per (b,c) ----------------
// Phases: load qz[b,c] (96x128) -> per head: project QU_h/QV_h (96x16),
// logits 96x96 (K=16), softmax over q, accumulate Abar in regs -> Abar LDS
// -> m_t = (1/8)*Abar @ qz.
__global__ __launch_bounds__(512, 1)
void tmsg_kernel(const float* __restrict__ qz, const float* __restrict__ wu,
                 const float* __restrict__ wv, float* __restrict__ out) {
  __shared__ __align__(16) float zq[NP * ND];     // swizzled [96][128]
  __shared__ __align__(16) float wst[32 * ND];    // swizzled [32][128]: rows 0..15 = U, 16..31 = V
  __shared__ float qu[NP * 17];                   // [96][17] padded, qu pre-scaled by 0.25
  __shared__ float qv[NP * 17];
  __shared__ float abar[NP * 97];                 // [96][97] padded

  const int tid = threadIdx.x;
  const int c = blockIdx.x, b = blockIdx.y;
  const float* zg = qz + (size_t)((b * NC + c) * NP) * ND;

  // load qz tile (swizzled)
  for (int i = tid; i < NP * 32; i += 512) {
    int p = i >> 5, s = i & 31;
    float4 v = reinterpret_cast<const float4*>(zg)[p * 32 + s];
    reinterpret_cast<float4*>(zq)[p * 32 + swz(s, p)] = v;
  }
  __syncthreads();

  const int lane = tid & 31;
  const int grp  = tid >> 5;   // 0..15
  const int r    = lane & 15;  // projection row within head
  const int mat  = lane >> 4;  // 0 = U, 1 = V
  const int tq   = tid & 15;   // logits col group
  const int tp   = tid >> 4;   // 0..31 logits row group

  float aacc[3][6];
#pragma unroll
  for (int i = 0; i < 3; ++i)
#pragma unroll
    for (int j = 0; j < 6; ++j) aacc[i][j] = 0.f;

  for (int h = 0; h < NH; ++h) {
    // stage W head-rows (16 U + 16 V), swizzled
    for (int i = tid; i < 32 * 32; i += 512) {
      int row = i >> 5, s = i & 31;
      const float* src = (row < 16 ? wu : wv) + (size_t)(b * ND + h * NR + (row & 15)) * ND;
      float4 v = reinterpret_cast<const float4*>(src)[s];
      reinterpret_cast<float4*>(wst)[row * 32 + swz(s, row)] = v;
    }
    __syncthreads();

    // projection: lane owns W row 'lane' (= mat*16+r) held in regs per 32-d chunk;
    // groups sweep p = grp + 16k. zq reads broadcast within a group.
    float acc[6] = {0, 0, 0, 0, 0, 0};
#pragma unroll
    for (int dc = 0; dc < 4; ++dc) {
      float4 w8[8];
#pragma unroll
      for (int j = 0; j < 8; ++j)
        w8[j] = reinterpret_cast<const float4*>(wst)[lane * 32 + swz(dc * 8 + j, lane)];
#pragma unroll
      for (int k = 0; k < 6; ++k) {
        int p = grp + 16 * k;
#pragma unroll
        for (int j = 0; j < 8; ++j) {
          float4 z = reinterpret_cast<const float4*>(zq)[p * 32 + swz(dc * 8 + j, p)];
          acc[k] += z.x * w8[j].x + z.y * w8[j].y + z.z * w8[j].z + z.w * w8[j].w;
        }
      }
    }
    {
      float* dst = mat ? qv : qu;
      float sc = mat ? 1.0f : 0.25f;  // fold logit scale 1/sqrt(R) into qu
#pragma unroll
      for (int k = 0; k < 6; ++k) dst[(grp + 16 * k) * 17 + r] = acc[k] * sc;
    }
    __syncthreads();

    // logits S[p][q], rows p = 3*tp+i, cols q = 6*tq+j ; K = 16
    float S[3][6];
#pragma unroll
    for (int i = 0; i < 3; ++i)
#pragma unroll
      for (int j = 0; j < 6; ++j) S[i][j] = 0.f;
    for (int rr = 0; rr < 16; ++rr) {
      float a0 = qu[(3 * tp + 0) * 17 + rr];
      float a1 = qu[(3 * tp + 1) * 17 + rr];
      float a2 = qu[(3 * tp + 2) * 17 + rr];
      float bb[6];
#pragma unroll
      for (int j = 0; j < 6; ++j) bb[j] = qv[(6 * tq + j) * 17 + rr];
#pragma unroll
      for (int j = 0; j < 6; ++j) {
        S[0][j] += a0 * bb[j];
        S[1][j] += a1 * bb[j];
        S[2][j] += a2 * bb[j];
      }
    }
    // softmax over q (row spread across the 16 lanes of this tp-group)
#pragma unroll
    for (int i = 0; i < 3; ++i) {
      float m = S[i][0];
#pragma unroll
      for (int j = 1; j < 6; ++j) m = fmaxf(m, S[i][j]);
#pragma unroll
      for (int off = 1; off < 16; off <<= 1) m = fmaxf(m, __shfl_xor(m, off, 16));
      float sum = 0.f;
#pragma unroll
      for (int j = 0; j < 6; ++j) { S[i][j] = __expf(S[i][j] - m); sum += S[i][j]; }
#pragma unroll
      for (int off = 1; off < 16; off <<= 1) sum += __shfl_xor(sum, off, 16);
      float inv = 1.0f / sum;
#pragma unroll
      for (int j = 0; j < 6; ++j) aacc[i][j] += S[i][j] * inv;
    }
    __syncthreads();  // protect wst/qu/qv for next head
  }

  // dump Abar (with 1/H fold) to LDS for the PV GEMM
#pragma unroll
  for (int i = 0; i < 3; ++i)
#pragma unroll
    for (int j = 0; j < 6; ++j)
      abar[(3 * tp + i) * 97 + (6 * tq + j)] = aacc[i][j] * 0.125f;
  __syncthreads();

  // PV: m_t[p][d] = sum_q Abar[p][q] * zq[q][d]; lane owns d-slot, groups own p rows
  float4 o[6];
#pragma unroll
  for (int k = 0; k < 6; ++k) o[k] = make_float4(0.f, 0.f, 0.f, 0.f);
  for (int q = 0; q < NP; ++q) {
    float4 z = reinterpret_cast<const float4*>(zq)[q * 32 + swz(lane, q)];
#pragma unroll
    for (int k = 0; k < 6; ++k) {
      float a = abar[(grp + 16 * k) * 97 + q];
      o[k].x += a * z.x; o[k].y += a * z.y; o[k].z += a * z.z; o[k].w += a * z.w;
    }
  }
  float4* og = reinterpret_cast<float4*>(out + (size_t)((b * NC + c) * NP) * ND);
#pragma unroll
  for (int k = 0; k < 6; ++k) og[(grp + 16 * k) * 32 + lane] = o[k];
}

// ---------------- channel-message kernel: one block per (b,p) ----------------
// m_c[b,c,p,d] = qz[b,c,p,d] * (1/8) sum_h softmax_d'(0.25*QUc QVc^T)[c,d]
// Abar lives entirely in registers (each thread owns its (c,d') cells across heads).
__global__ __launch_bounds__(512, 1)
void cmsg_kernel(const float* __restrict__ qz, const float* __restrict__ wu,
                 const float* __restrict__ wv, float* __restrict__ out) {
  __shared__ __align__(16) float zc[NC * ND];   // swizzled [128][128]
  __shared__ __align__(16) float wst[32 * ND];
  __shared__ float qu[NC * 18];                 // [128][18] padded, pre-scaled 0.25
  __shared__ float qv[NC * 18];

  const int tid = threadIdx.x;
  const int p = blockIdx.x, b = blockIdx.y;

  for (int i = tid; i < NC * 32; i += 512) {
    int cc = i >> 5, s = i & 31;
    const float* src = qz + (size_t)((b * NC + cc) * NP + p) * ND;
    float4 v = reinterpret_cast<const float4*>(src)[s];
    reinterpret_cast<float4*>(zc)[cc * 32 + swz(s, cc)] = v;
  }
  __syncthreads();

  const int lane = tid & 31, grp = tid >> 5;
  const int r = lane & 15, mat = lane >> 4;
  const int tq = tid & 15, tp = tid >> 4;  // rows c = 4*tp+i, cols d' = 8*tq+j

  float aacc[4][8];
#pragma unroll
  for (int i = 0; i < 4; ++i)
#pragma unroll
    for (int j = 0; j < 8; ++j) aacc[i][j] = 0.f;

  for (int h = 0; h < NH; ++h) {
    for (int i = tid; i < 32 * 32; i += 512) {
      int row = i >> 5, s = i & 31;
      const float* src = (row < 16 ? wu : wv) + (size_t)(b * ND + h * NR + (row & 15)) * ND;
      float4 v = reinterpret_cast<const float4*>(src)[s];
      reinterpret_cast<float4*>(wst)[row * 32 + swz(s, row)] = v;
    }
    __syncthreads();

    float acc[8] = {0, 0, 0, 0, 0, 0, 0, 0};
#pragma unroll
    for (int dc = 0; dc < 4; ++dc) {
      float4 w8[8];
#pragma unroll
      for (int j = 0; j < 8; ++j)
        w8[j] = reinterpret_cast<const float4*>(wst)[lane * 32 + swz(dc * 8 + j, lane)];
#pragma unroll
      for (int k = 0; k < 8; ++k) {
        int cc = grp + 16 * k;
#pragma unroll
        for (int j = 0; j < 8; ++j) {
          float4 z = reinterpret_cast<const float4*>(zc)[cc * 32 + swz(dc * 8 + j, cc)];
          acc[k] += z.x * w8[j].x + z.y * w8[j].y + z.z * w8[j].z + z.w * w8[j].w;
        }
      }
    }
    {
      float* dst = mat ? qv : qu;
      float sc = mat ? 1.0f : 0.25f;
#pragma unroll
      for (int k = 0; k < 8; ++k) dst[(grp + 16 * k) * 18 + r] = acc[k] * sc;
    }
    __syncthreads();

    float S[4][8];
#pragma unroll
    for (int i = 0; i < 4; ++i)
#pragma unroll
      for (int j = 0; j < 8; ++j) S[i][j] = 0.f;
    for (int rr = 0; rr < 16; ++rr) {
      float aa[4];
#pragma unroll
      for (int i = 0; i < 4; ++i) aa[i] = qu[(4 * tp + i) * 18 + rr];
      float bb[8];
#pragma unroll
      for (int j = 0; j < 8; ++j) bb[j] = qv[(8 * tq + j) * 18 + rr];
#pragma unroll
      for (int i = 0; i < 4; ++i)
#pragma unroll
        for (int j = 0; j < 8; ++j) S[i][j] += aa[i] * bb[j];
    }
#pragma unroll
    for (int i = 0; i < 4; ++i) {
      float m = S[i][0];
#pragma unroll
      for (int j = 1; j < 8; ++j) m = fmaxf(m, S[i][j]);
#pragma unroll
      for (int off = 1; off < 16; off <<= 1) m = fmaxf(m, __shfl_xor(m, off, 16));
      float sum = 0.f;
#pragma unroll
      for (int j = 0; j < 8; ++j) { S[i][j] = __expf(S[i][j] - m); sum += S[i][j]; }
#pragma unroll
      for (int off = 1; off < 16; off <<= 1) sum += __shfl_xor(sum, off, 16);
      float inv = 1.0f / sum;
#pragma unroll
      for (int j = 0; j < 8; ++j) aacc[i][j] += S[i][j] * inv;
    }
    __syncthreads();
  }

  // elementwise finish: m_c = (aacc/8) * qz  (qz re-read from global, L2-hot)
#pragma unroll
  for (int i = 0; i < 4; ++i) {
    int cc = 4 * tp + i;
    const float* zrow = qz + (size_t)((b * NC + cc) * NP + p) * ND;
    float4 z0 = reinterpret_cast<const float4*>(zrow)[2 * tq];
    float4 z1 = reinterpret_cast<const float4*>(zrow)[2 * tq + 1];
    float4 o0, o1;
    o0.x = aacc[i][0] * 0.125f * z0.x;
    o0.y = aacc[i][1] * 0.125f * z0.y;
    o0.z = aacc[i][2] * 0.125f * z0.z;
    o0.w = aacc[i][3] * 0.125f * z0.w;
    o1.x = aacc[i][4] * 0.125f * z1.x;
    o1.y = aacc[i][5] * 0.125f * z1.y;
    o1.z = aacc[i][6] * 0.125f * z1.z;
    o1.w = aacc[i][7] * 0.125f * z1.w;
    float4* orow = reinterpret_cast<float4*>(out + (size_t)((b * NC + cc) * NP + p) * ND);
    orow[2 * tq] = o0;
    orow[2 * tq + 1] = o1;
  }
}

extern "C" void kernel_launch(void* const* d_in, const int* in_sizes, int n_in,
                              void* d_out, int out_size, void* d_ws, size_t ws_size,
                              hipStream_t stream) {
  const float* qz  = (const float*)d_in[0];
  const float* tuw = (const float*)d_in[1];
  const float* tvw = (const float*)d_in[2];
  const float* cuw = (const float*)d_in[3];
  const float* cvw = (const float*)d_in[4];
  float* out_t = (float*)d_out;
  float* out_c = out_t + (size_t)NB * NC * NP * ND;

  tmsg_kernel<<<dim3(NC, NB), 512, 0, stream>>>(qz, tuw, tvw, out_t);
  cmsg_kernel<<<dim3(NP, NB), 512, 0, stream>>>(qz, cuw, cvw, out_c);
}

// Round 4
// 318.620 us; speedup vs baseline: 1.9626x; 1.9626x over previous
//
#include <hip/hip_runtime.h>
#include <math.h>

#define NB 8
#define NC 128
#define NP 96
#define ND 128
#define NH 8
#define NR 16

typedef __attribute__((ext_vector_type(8))) short short8;
typedef __attribute__((ext_vector_type(4))) float f32x4;

#define MFMA(a, b, c) __builtin_amdgcn_mfma_f32_16x16x32_bf16((a), (b), (c), 0, 0, 0)

// round-to-nearest-even fp32 -> bf16 (as short)
__device__ __forceinline__ short bf_hi(float x) {
  unsigned u = __float_as_uint(x);
  unsigned r = u + 0x7fffu + ((u >> 16) & 1u);
  return (short)(r >> 16);
}
__device__ __forceinline__ float bf_f(short s) {
  return __uint_as_float(((unsigned)(unsigned short)s) << 16);
}

// LDS row strides in shorts (all rows 16B-aligned; strides chosen so that
// 16-lane row-strided ds_read_b128 lands on distinct bank groups: <=2-way)
#define TS_Z 136   // z      [rows][136]
#define TS_Q 72    // Q2     [rows][72]
#define TS_T 104   // zT/abar[rows][104]

// ---------------- time-message kernel: one block per (b,c) ----------------
// phase1 LDS: z split [96][136] + Q2 split [96][72]  = 79872 B
// phase2 LDS (aliased): zT split [128][104] + abar-hi [96][104] = 73216 B
__global__ __launch_bounds__(512, 4)
void tmsg_kernel(const float* __restrict__ qz, const float* __restrict__ wu,
                 const float* __restrict__ wv, float* __restrict__ out) {
  __shared__ __align__(16) short smem[39936];
  short* zhi = smem;                   // [96][136]
  short* zlo = smem + NP * TS_Z;
  short* qhi = smem + 2 * NP * TS_Z;   // [96][72]
  short* qlo = qhi + NP * TS_Q;
  short* zthi = smem;                  // [128][104] (phase2)
  short* ztlo = smem + ND * TS_T;
  short* ahi  = smem + 2 * ND * TS_T;  // [96][104]  (phase2)

  const int tid = threadIdx.x;
  const int l = tid & 63, w = tid >> 6;
  const int lm = l & 15, lk = l >> 4;
  const int c = blockIdx.x, b = blockIdx.y;
  const float* zg = qz + ((size_t)(b * NC + c) * NP) * ND;

  // ---- load z -> split bf16, row-major ----
  for (int i = tid; i < NP * 32; i += 512) {
    int p = i >> 5, s = i & 31;
    float4 v = reinterpret_cast<const float4*>(zg)[i];
    short h0 = bf_hi(v.x), h1 = bf_hi(v.y), h2 = bf_hi(v.z), h3 = bf_hi(v.w);
    *(short4*)&zhi[p * TS_Z + 4 * s] = make_short4(h0, h1, h2, h3);
    *(short4*)&zlo[p * TS_Z + 4 * s] =
        make_short4(bf_hi(v.x - bf_f(h0)), bf_hi(v.y - bf_f(h1)),
                    bf_hi(v.z - bf_f(h2)), bf_hi(v.w - bf_f(h3)));
  }
  __syncthreads();

  float aacc[4][6];
#pragma unroll
  for (int r = 0; r < 4; ++r)
#pragma unroll
    for (int nt = 0; nt < 6; ++nt) aacc[r][nt] = 0.f;

  const short8 z8 = {0, 0, 0, 0, 0, 0, 0, 0};
  const f32x4 zf = {0.f, 0.f, 0.f, 0.f};

  for (int hp = 0; hp < 4; ++hp) {
    // ---- projection for heads 2hp,2hp+1: Q[96][64], tiles t=3w..3w+2 ----
    f32x4 pacc[3] = {zf, zf, zf};
#pragma unroll
    for (int ks = 0; ks < 4; ++ks) {
#pragma unroll
      for (int tt = 0; tt < 3; ++tt) {
        int t = 3 * w + tt, m = t >> 2, nt = t & 3;
        short8 ah = *(const short8*)&zhi[(m * 16 + lm) * TS_Z + ks * 32 + lk * 8];
        short8 al = *(const short8*)&zlo[(m * 16 + lm) * TS_Z + ks * 32 + lk * 8];
        int hd = 2 * hp + (nt >> 1);
        const float* wmat = (nt & 1) ? wv : wu;
        const float* wrow = wmat + ((size_t)b * ND + hd * NR + lm) * ND + ks * 32 + lk * 8;
        float4 x0 = *(const float4*)wrow;
        float4 x1 = *(const float4*)(wrow + 4);
        float f[8] = {x0.x, x0.y, x0.z, x0.w, x1.x, x1.y, x1.z, x1.w};
        short8 bh, bl;
#pragma unroll
        for (int j = 0; j < 8; ++j) {
          short hh = bf_hi(f[j]);
          bh[j] = hh;
          bl[j] = bf_hi(f[j] - bf_f(hh));
        }
        pacc[tt] = MFMA(ah, bh, pacc[tt]);
        pacc[tt] = MFMA(ah, bl, pacc[tt]);
        pacc[tt] = MFMA(al, bh, pacc[tt]);
      }
    }
#pragma unroll
    for (int tt = 0; tt < 3; ++tt) {
      int t = 3 * w + tt, m = t >> 2, nt = t & 3;
      float sc = (nt & 1) ? 1.0f : 0.25f;  // fold logit scale into Qu
#pragma unroll
      for (int r = 0; r < 4; ++r) {
        float v = pacc[tt][r] * sc;
        int row = m * 16 + lk * 4 + r, col = nt * 16 + lm;
        short hh = bf_hi(v);
        qhi[row * TS_Q + col] = hh;
        qlo[row * TS_Q + col] = bf_hi(v - bf_f(hh));
      }
    }
    __syncthreads();

    // ---- logits (K=16 zero-padded) + softmax; waves 0-5 own m-tiles ----
    if (w < 6) {
#pragma unroll
      for (int hh = 0; hh < 2; ++hh) {
        short8 ah = z8, al = z8;
        if (l < 32) {
          ah = *(const short8*)&qhi[(w * 16 + lm) * TS_Q + 32 * hh + lk * 8];
          al = *(const short8*)&qlo[(w * 16 + lm) * TS_Q + 32 * hh + lk * 8];
        }
        f32x4 s[6];
#pragma unroll
        for (int nt = 0; nt < 6; ++nt) {
          s[nt] = zf;
          short8 bh = z8, bl = z8;
          if (l < 32) {
            bh = *(const short8*)&qhi[(nt * 16 + lm) * TS_Q + 32 * hh + 16 + lk * 8];
            bl = *(const short8*)&qlo[(nt * 16 + lm) * TS_Q + 32 * hh + 16 + lk * 8];
          }
          s[nt] = MFMA(ah, bh, s[nt]);
          s[nt] = MFMA(ah, bl, s[nt]);
          s[nt] = MFMA(al, bh, s[nt]);
        }
#pragma unroll
        for (int r = 0; r < 4; ++r) {
          float mx = s[0][r];
#pragma unroll
          for (int nt = 1; nt < 6; ++nt) mx = fmaxf(mx, s[nt][r]);
          mx = fmaxf(mx, __shfl_xor(mx, 1));
          mx = fmaxf(mx, __shfl_xor(mx, 2));
          mx = fmaxf(mx, __shfl_xor(mx, 4));
          mx = fmaxf(mx, __shfl_xor(mx, 8));
          float e[6], sum = 0.f;
#pragma unroll
          for (int nt = 0; nt < 6; ++nt) { e[nt] = __expf(s[nt][r] - mx); sum += e[nt]; }
          sum += __shfl_xor(sum, 1);
          sum += __shfl_xor(sum, 2);
          sum += __shfl_xor(sum, 4);
          sum += __shfl_xor(sum, 8);
          float inv = 1.0f / sum;
#pragma unroll
          for (int nt = 0; nt < 6; ++nt) aacc[r][nt] += e[nt] * inv;
        }
      }
    }
    __syncthreads();
  }

  // ---- phase2: build zT split + abar-hi in aliased LDS ----
  for (int i = tid; i < NP * 32; i += 512) {
    int p = i >> 5, s = i & 31;
    float4 v = reinterpret_cast<const float4*>(zg)[i];
    float f[4] = {v.x, v.y, v.z, v.w};
#pragma unroll
    for (int j = 0; j < 4; ++j) {
      int d = 4 * s + j;
      short hh = bf_hi(f[j]);
      zthi[d * TS_T + p] = hh;
      ztlo[d * TS_T + p] = bf_hi(f[j] - bf_f(hh));
    }
  }
  if (w < 6) {
#pragma unroll
    for (int r = 0; r < 4; ++r)
#pragma unroll
      for (int nt = 0; nt < 6; ++nt)
        ahi[(w * 16 + lk * 4 + r) * TS_T + nt * 16 + lm] = bf_hi(aacc[r][nt] * 0.125f);
  }
  __syncthreads();

  // ---- PV: m_t = abar @ z ; wave w owns d-tile w; K=96 ----
  float* og = out + ((size_t)(b * NC + c) * NP) * ND;
  f32x4 oacc[6] = {zf, zf, zf, zf, zf, zf};
#pragma unroll
  for (int ks = 0; ks < 3; ++ks) {
    short8 bh = *(const short8*)&zthi[(w * 16 + lm) * TS_T + ks * 32 + lk * 8];
    short8 bl = *(const short8*)&ztlo[(w * 16 + lm) * TS_T + ks * 32 + lk * 8];
#pragma unroll
    for (int m = 0; m < 6; ++m) {
      short8 a = *(const short8*)&ahi[(m * 16 + lm) * TS_T + ks * 32 + lk * 8];
      oacc[m] = MFMA(a, bh, oacc[m]);
      oacc[m] = MFMA(a, bl, oacc[m]);
    }
  }
#pragma unroll
  for (int m = 0; m < 6; ++m)
#pragma unroll
    for (int r = 0; r < 4; ++r)
      og[(m * 16 + lk * 4 + r) * ND + w * 16 + lm] = oacc[m][r];
}

// ---------------- channel-message kernel: one block per (b,p) ----------------
// LDS: z split [128][136] + Q2 split [128][72] = 106496 B. abar stays in regs.
__global__ __launch_bounds__(512, 2)
void cmsg_kernel(const float* __restrict__ qz, const float* __restrict__ wu,
                 const float* __restrict__ wv, float* __restrict__ out) {
  __shared__ __align__(16) short smem[53248];
  short* zhi = smem;                   // [128][136]
  short* zlo = smem + NC * TS_Z;
  short* qhi = smem + 2 * NC * TS_Z;   // [128][72]
  short* qlo = qhi + NC * TS_Q;

  const int tid = threadIdx.x;
  const int l = tid & 63, w = tid >> 6;
  const int lm = l & 15, lk = l >> 4;
  const int p = blockIdx.x, b = blockIdx.y;

  for (int i = tid; i < NC * 32; i += 512) {
    int cc = i >> 5, s = i & 31;
    float4 v = reinterpret_cast<const float4*>(qz + ((size_t)(b * NC + cc) * NP + p) * ND)[s];
    short h0 = bf_hi(v.x), h1 = bf_hi(v.y), h2 = bf_hi(v.z), h3 = bf_hi(v.w);
    *(short4*)&zhi[cc * TS_Z + 4 * s] = make_short4(h0, h1, h2, h3);
    *(short4*)&zlo[cc * TS_Z + 4 * s] =
        make_short4(bf_hi(v.x - bf_f(h0)), bf_hi(v.y - bf_f(h1)),
                    bf_hi(v.z - bf_f(h2)), bf_hi(v.w - bf_f(h3)));
  }
  __syncthreads();

  float aacc[4][8];
#pragma unroll
  for (int r = 0; r < 4; ++r)
#pragma unroll
    for (int nt = 0; nt < 8; ++nt) aacc[r][nt] = 0.f;

  const short8 z8 = {0, 0, 0, 0, 0, 0, 0, 0};
  const f32x4 zf = {0.f, 0.f, 0.f, 0.f};

  for (int hp = 0; hp < 4; ++hp) {
    // ---- projection: wave w = m-tile (c rows), 4 n-tiles each ----
    f32x4 pacc[4] = {zf, zf, zf, zf};
#pragma unroll
    for (int ks = 0; ks < 4; ++ks) {
      short8 ah = *(const short8*)&zhi[(w * 16 + lm) * TS_Z + ks * 32 + lk * 8];
      short8 al = *(const short8*)&zlo[(w * 16 + lm) * TS_Z + ks * 32 + lk * 8];
#pragma unroll
      for (int nt = 0; nt < 4; ++nt) {
        int hd = 2 * hp + (nt >> 1);
        const float* wmat = (nt & 1) ? wv : wu;
        const float* wrow = wmat + ((size_t)b * ND + hd * NR + lm) * ND + ks * 32 + lk * 8;
        float4 x0 = *(const float4*)wrow;
        float4 x1 = *(const float4*)(wrow + 4);
        float f[8] = {x0.x, x0.y, x0.z, x0.w, x1.x, x1.y, x1.z, x1.w};
        short8 bh, bl;
#pragma unroll
        for (int j = 0; j < 8; ++j) {
          short hh = bf_hi(f[j]);
          bh[j] = hh;
          bl[j] = bf_hi(f[j] - bf_f(hh));
        }
        pacc[nt] = MFMA(ah, bh, pacc[nt]);
        pacc[nt] = MFMA(ah, bl, pacc[nt]);
        pacc[nt] = MFMA(al, bh, pacc[nt]);
      }
    }
#pragma unroll
    for (int nt = 0; nt < 4; ++nt) {
      float sc = (nt & 1) ? 1.0f : 0.25f;
#pragma unroll
      for (int r = 0; r < 4; ++r) {
        float v = pacc[nt][r] * sc;
        int row = w * 16 + lk * 4 + r, col = nt * 16 + lm;
        short hh = bf_hi(v);
        qhi[row * TS_Q + col] = hh;
        qlo[row * TS_Q + col] = bf_hi(v - bf_f(hh));
      }
    }
    __syncthreads();

    // ---- logits (K=16 padded) + softmax over d' ----
#pragma unroll
    for (int hh = 0; hh < 2; ++hh) {
      short8 ah = z8, al = z8;
      if (l < 32) {
        ah = *(const short8*)&qhi[(w * 16 + lm) * TS_Q + 32 * hh + lk * 8];
        al = *(const short8*)&qlo[(w * 16 + lm) * TS_Q + 32 * hh + lk * 8];
      }
      f32x4 s[8];
#pragma unroll
      for (int nt = 0; nt < 8; ++nt) {
        s[nt] = zf;
        short8 bh = z8, bl = z8;
        if (l < 32) {
          bh = *(const short8*)&qhi[(nt * 16 + lm) * TS_Q + 32 * hh + 16 + lk * 8];
          bl = *(const short8*)&qlo[(nt * 16 + lm) * TS_Q + 32 * hh + 16 + lk * 8];
        }
        s[nt] = MFMA(ah, bh, s[nt]);
        s[nt] = MFMA(ah, bl, s[nt]);
        s[nt] = MFMA(al, bh, s[nt]);
      }
#pragma unroll
      for (int r = 0; r < 4; ++r) {
        float mx = s[0][r];
#pragma unroll
        for (int nt = 1; nt < 8; ++nt) mx = fmaxf(mx, s[nt][r]);
        mx = fmaxf(mx, __shfl_xor(mx, 1));
        mx = fmaxf(mx, __shfl_xor(mx, 2));
        mx = fmaxf(mx, __shfl_xor(mx, 4));
        mx = fmaxf(mx, __shfl_xor(mx, 8));
        float e[8], sum = 0.f;
#pragma unroll
        for (int nt = 0; nt < 8; ++nt) { e[nt] = __expf(s[nt][r] - mx); sum += e[nt]; }
        sum += __shfl_xor(sum, 1);
        sum += __shfl_xor(sum, 2);
        sum += __shfl_xor(sum, 4);
        sum += __shfl_xor(sum, 8);
        float inv = 1.0f / sum;
#pragma unroll
        for (int nt = 0; nt < 8; ++nt) aacc[r][nt] += e[nt] * inv;
      }
    }
    __syncthreads();
  }

  // ---- elementwise finish: m_c = (abar/8) * z (z rebuilt from split LDS) ----
#pragma unroll
  for (int r = 0; r < 4; ++r) {
    int cc = w * 16 + lk * 4 + r;
#pragma unroll
    for (int nt = 0; nt < 8; ++nt) {
      int d = nt * 16 + lm;
      float zv = bf_f(zhi[cc * TS_Z + d]) + bf_f(zlo[cc * TS_Z + d]);
      out[((size_t)(b * NC + cc) * NP + p) * ND + d] = 0.125f * aacc[r][nt] * zv;
    }
  }
}

extern "C" void kernel_launch(void* const* d_in, const int* in_sizes, int n_in,
                              void* d_out, int out_size, void* d_ws, size_t ws_size,
                              hipStream_t stream) {
  const float* qz  = (const float*)d_in[0];
  const float* tuw = (const float*)d_in[1];
  const float* tvw = (const float*)d_in[2];
  const float* cuw = (const float*)d_in[3];
  const float* cvw = (const float*)d_in[4];
  float* out_t = (float*)d_out;
  float* out_c = out_t + (size_t)NB * NC * NP * ND;

  tmsg_kernel<<<dim3(NC, NB), 512, 0, stream>>>(qz, tuw, tvw, out_t);
  cmsg_kernel<<<dim3(NP, NB), 512, 0, stream>>>(qz, cuw, cvw, out_c);
}

// Round 6
// 211.909 us; speedup vs baseline: 2.9509x; 1.5036x over previous
//
#include <hip/hip_runtime.h>
#include <math.h>

#define NB 8
#define NC 128
#define NP 96
#define ND 128
#define NH 8
#define NR 16

typedef __attribute__((ext_vector_type(8))) short short8;
typedef __attribute__((ext_vector_type(4))) float f32x4;
typedef __attribute__((ext_vector_type(4))) unsigned u32x4;

#define MFMA(a, b, c) __builtin_amdgcn_mfma_f32_16x16x32_bf16((a), (b), (c), 0, 0, 0)

__device__ __forceinline__ short8 s8(u32x4 u) { return __builtin_bit_cast(short8, u); }

// scalar fp32 -> bf16 (RNE) and back
__device__ __forceinline__ unsigned bfh_u(float x) {
  unsigned u = __float_as_uint(x);
  unsigned r = u + 0x7fffu + ((u >> 16) & 1u);
  return r >> 16;  // bf16 bits in low 16
}
__device__ __forceinline__ short bfh(float x) { return (short)bfh_u(x); }
__device__ __forceinline__ float bff(short s) {
  return __uint_as_float(((unsigned)(unsigned short)s) << 16);
}

// pair split: {hi_packed, lo_packed}, elem a in low 16 bits of each word
__device__ __forceinline__ uint2 split2(float a, float b) {
  unsigned ha = bfh_u(a), hb = bfh_u(b);
  float fa = __uint_as_float(ha << 16), fb = __uint_as_float(hb << 16);
  unsigned la = bfh_u(a - fa), lb = bfh_u(b - fb);
  return make_uint2(ha | (hb << 16), la | (lb << 16));
}

// LDS row strides in shorts
#define TS_Z 136   // z      [rows][136]
#define TS_Q 72    // Q2     [rows][72]
#define TS_T 104   // zT/abar[rows][104]

#define W_ELEMS ((size_t)4 * 8 * 128 * 128)  // 524288 per split
#define W_NEED (W_ELEMS * 2 * 2)             // 2 MB

// ---------------- W split precompute: mats {tu, tv, cu, cv} ----------------
__global__ __launch_bounds__(256)
void prep_w(const float* __restrict__ w0, const float* __restrict__ w1,
            const float* __restrict__ w2, const float* __restrict__ w3,
            short* __restrict__ whi, short* __restrict__ wlo) {
  int t = blockIdx.x * 256 + threadIdx.x;   // 65536 threads, 8 elems each
  int mat = t >> 14;
  size_t off = (size_t)(t & 16383) * 8;
  const float* srcs[4] = {w0, w1, w2, w3};
  const float* s = srcs[mat] + off;
  float4 a = *(const float4*)s, b = *(const float4*)(s + 4);
  uint2 r0 = split2(a.x, a.y), r1 = split2(a.z, a.w);
  uint2 r2 = split2(b.x, b.y), r3 = split2(b.z, b.w);
  size_t base = (size_t)mat * 131072 + off;
  *(u32x4*)&whi[base] = u32x4{r0.x, r1.x, r2.x, r3.x};
  *(u32x4*)&wlo[base] = u32x4{r0.y, r1.y, r2.y, r3.y};
}

// ---------------- time-message kernel: one block per (b,c) ----------------
template <int WS>
__global__ __launch_bounds__(512, 4)
void tmsg_kernel(const float* __restrict__ qz, const float* __restrict__ wu,
                 const float* __restrict__ wv, const short* __restrict__ whi,
                 const short* __restrict__ wlo, float* __restrict__ out) {
  __shared__ __align__(16) short smem[39936];
  short* zhi = smem;                   // [96][136]
  short* zlo = smem + NP * TS_Z;
  short* qhi = smem + 2 * NP * TS_Z;   // [96][72]
  short* qlo = qhi + NP * TS_Q;
  short* zthi = smem;                  // [128][104] (phase2, aliased)
  short* ztlo = smem + ND * TS_T;
  short* ahi  = smem + 2 * ND * TS_T;  // [96][104]  (phase2)

  const int tid = threadIdx.x;
  const int l = tid & 63, w = tid >> 6;
  const int lm = l & 15, lk = l >> 4;
  const int c = blockIdx.x, b = blockIdx.y;
  const float* zg = qz + ((size_t)(b * NC + c) * NP) * ND;

  // ---- stage z -> split bf16 ----
  for (int i = tid; i < NP * 32; i += 512) {
    int p = i >> 5, s = i & 31;
    float4 v = ((const float4*)zg)[i];
    uint2 r0 = split2(v.x, v.y), r1 = split2(v.z, v.w);
    *(uint2*)&zhi[p * TS_Z + 4 * s] = make_uint2(r0.x, r1.x);
    *(uint2*)&zlo[p * TS_Z + 4 * s] = make_uint2(r0.y, r1.y);
  }
  __syncthreads();

  const int nt = w & 3, mset = (w >> 2) * 3;  // wave owns fixed nt, 3 m-tiles
  const int vsel = nt & 1, hsel = nt >> 1;
  const float qsc = vsel ? 1.0f : 0.25f;  // fold 1/sqrt(R) into Qu

  float aacc[4][6] = {};
  const short8 z8 = {0, 0, 0, 0, 0, 0, 0, 0};
  const f32x4 zf = {0.f, 0.f, 0.f, 0.f};

  for (int hp = 0; hp < 4; ++hp) {
    const int hd = 2 * hp + hsel;
    // ---- W fragments for this wave's nt: hoisted out of the tile loop ----
    u32x4 wbh[4], wbl[4];
    if constexpr (WS) {
      const size_t rb = (((size_t)vsel * 8 + b) * 128 + hd * NR + lm) * 128;
#pragma unroll
      for (int ks = 0; ks < 4; ++ks) {
        wbh[ks] = *(const u32x4*)&whi[rb + ks * 32 + lk * 8];
        wbl[ks] = *(const u32x4*)&wlo[rb + ks * 32 + lk * 8];
      }
    } else {
      const float* wrow = (vsel ? wv : wu) + ((size_t)b * ND + hd * NR + lm) * ND;
#pragma unroll
      for (int ks = 0; ks < 4; ++ks) {
        float4 x0 = *(const float4*)(wrow + ks * 32 + lk * 8);
        float4 x1 = *(const float4*)(wrow + ks * 32 + lk * 8 + 4);
        uint2 r0 = split2(x0.x, x0.y), r1 = split2(x0.z, x0.w);
        uint2 r2 = split2(x1.x, x1.y), r3 = split2(x1.z, x1.w);
        wbh[ks] = u32x4{r0.x, r1.x, r2.x, r3.x};
        wbl[ks] = u32x4{r0.y, r1.y, r2.y, r3.y};
      }
    }
    // ---- projection: Q tiles (m, nt) for m in mset..mset+2 ----
    f32x4 pacc[3] = {zf, zf, zf};
#pragma unroll
    for (int ks = 0; ks < 4; ++ks) {
#pragma unroll
      for (int mm = 0; mm < 3; ++mm) {
        int row = (mset + mm) * 16 + lm;
        short8 ah = *(const short8*)&zhi[row * TS_Z + ks * 32 + lk * 8];
        short8 al = *(const short8*)&zlo[row * TS_Z + ks * 32 + lk * 8];
        pacc[mm] = MFMA(ah, s8(wbh[ks]), pacc[mm]);
        pacc[mm] = MFMA(ah, s8(wbl[ks]), pacc[mm]);
        pacc[mm] = MFMA(al, s8(wbh[ks]), pacc[mm]);
      }
    }
#pragma unroll
    for (int mm = 0; mm < 3; ++mm) {
#pragma unroll
      for (int r = 0; r < 4; ++r) {
        float v = pacc[mm][r] * qsc;
        int row = (mset + mm) * 16 + lk * 4 + r, col = nt * 16 + lm;
        short hh = bfh(v);
        qhi[row * TS_Q + col] = hh;
        qlo[row * TS_Q + col] = bfh(v - bff(hh));
      }
    }
    __syncthreads();

    // ---- logits (K=16 zero-padded) + softmax; waves 0-5 own m-tiles ----
    if (w < 6) {
#pragma unroll
      for (int hh = 0; hh < 2; ++hh) {
        short8 ah = z8, al = z8;
        if (l < 32) {
          ah = *(const short8*)&qhi[(w * 16 + lm) * TS_Q + 32 * hh + lk * 8];
          al = *(const short8*)&qlo[(w * 16 + lm) * TS_Q + 32 * hh + lk * 8];
        }
        f32x4 s[6];
#pragma unroll
        for (int qt = 0; qt < 6; ++qt) {
          s[qt] = zf;
          short8 bh = z8, bl = z8;
          if (l < 32) {
            bh = *(const short8*)&qhi[(qt * 16 + lm) * TS_Q + 32 * hh + 16 + lk * 8];
            bl = *(const short8*)&qlo[(qt * 16 + lm) * TS_Q + 32 * hh + 16 + lk * 8];
          }
          s[qt] = MFMA(ah, bh, s[qt]);
          s[qt] = MFMA(ah, bl, s[qt]);
          s[qt] = MFMA(al, bh, s[qt]);
        }
#pragma unroll
        for (int r = 0; r < 4; ++r) {
          float mx = s[0][r];
#pragma unroll
          for (int qt = 1; qt < 6; ++qt) mx = fmaxf(mx, s[qt][r]);
          mx = fmaxf(mx, __shfl_xor(mx, 1));
          mx = fmaxf(mx, __shfl_xor(mx, 2));
          mx = fmaxf(mx, __shfl_xor(mx, 4));
          mx = fmaxf(mx, __shfl_xor(mx, 8));
          float e[6], sum = 0.f;
#pragma unroll
          for (int qt = 0; qt < 6; ++qt) { e[qt] = __expf(s[qt][r] - mx); sum += e[qt]; }
          sum += __shfl_xor(sum, 1);
          sum += __shfl_xor(sum, 2);
          sum += __shfl_xor(sum, 4);
          sum += __shfl_xor(sum, 8);
          float inv = 1.0f / sum;
#pragma unroll
          for (int qt = 0; qt < 6; ++qt) aacc[r][qt] += e[qt] * inv;
        }
      }
    }
    __syncthreads();
  }

  // ---- phase2: build zT split + abar-hi in aliased LDS ----
  for (int i = tid; i < NP * 32; i += 512) {
    int p = i >> 5, s = i & 31;
    float4 v = ((const float4*)zg)[i];
    float f[4] = {v.x, v.y, v.z, v.w};
#pragma unroll
    for (int j = 0; j < 4; ++j) {
      int d = 4 * s + j;
      short hh = bfh(f[j]);
      zthi[d * TS_T + p] = hh;
      ztlo[d * TS_T + p] = bfh(f[j] - bff(hh));
    }
  }
  if (w < 6) {
#pragma unroll
    for (int r = 0; r < 4; ++r)
#pragma unroll
      for (int qt = 0; qt < 6; ++qt)
        ahi[(w * 16 + lk * 4 + r) * TS_T + qt * 16 + lm] = bfh(aacc[r][qt] * 0.125f);
  }
  __syncthreads();

  // ---- PV: m_t = abar @ z ; wave w owns d-tile w; K=96 ----
  float* og = out + ((size_t)(b * NC + c) * NP) * ND;
  f32x4 oacc[6] = {zf, zf, zf, zf, zf, zf};
#pragma unroll
  for (int ks = 0; ks < 3; ++ks) {
    short8 bh = *(const short8*)&zthi[(w * 16 + lm) * TS_T + ks * 32 + lk * 8];
    short8 bl = *(const short8*)&ztlo[(w * 16 + lm) * TS_T + ks * 32 + lk * 8];
#pragma unroll
    for (int m = 0; m < 6; ++m) {
      short8 a = *(const short8*)&ahi[(m * 16 + lm) * TS_T + ks * 32 + lk * 8];
      oacc[m] = MFMA(a, bh, oacc[m]);
      oacc[m] = MFMA(a, bl, oacc[m]);
    }
  }
#pragma unroll
  for (int m = 0; m < 6; ++m)
#pragma unroll
    for (int r = 0; r < 4; ++r)
      og[(m * 16 + lk * 4 + r) * ND + w * 16 + lm] = oacc[m][r];
}

// ---------------- channel-message kernel: one block per (b,p) ----------------
template <int WS>
__global__ __launch_bounds__(512, 2)
void cmsg_kernel(const float* __restrict__ qz, const float* __restrict__ wu,
                 const float* __restrict__ wv, const short* __restrict__ whi,
                 const short* __restrict__ wlo, float* __restrict__ out) {
  __shared__ __align__(16) short smem[53248];
  short* zhi = smem;                   // [128][136]
  short* zlo = smem + NC * TS_Z;
  short* qhi = smem + 2 * NC * TS_Z;   // [128][72]
  short* qlo = qhi + NC * TS_Q;

  const int tid = threadIdx.x;
  const int l = tid & 63, w = tid >> 6;
  const int lm = l & 15, lk = l >> 4;
  const int p = blockIdx.x, b = blockIdx.y;

  for (int i = tid; i < NC * 32; i += 512) {
    int cc = i >> 5, s = i & 31;
    float4 v = ((const float4*)(qz + ((size_t)(b * NC + cc) * NP + p) * ND))[s];
    uint2 r0 = split2(v.x, v.y), r1 = split2(v.z, v.w);
    *(uint2*)&zhi[cc * TS_Z + 4 * s] = make_uint2(r0.x, r1.x);
    *(uint2*)&zlo[cc * TS_Z + 4 * s] = make_uint2(r0.y, r1.y);
  }
  __syncthreads();

  const int nt = w & 3, mset = (w >> 2) * 4;  // fixed nt, 4 m-tiles
  const int vsel = nt & 1, hsel = nt >> 1;
  const float qsc = vsel ? 1.0f : 0.25f;

  float aacc[4][8] = {};
  const short8 z8 = {0, 0, 0, 0, 0, 0, 0, 0};
  const f32x4 zf = {0.f, 0.f, 0.f, 0.f};

  for (int hp = 0; hp < 4; ++hp) {
    const int hd = 2 * hp + hsel;
    u32x4 wbh[4], wbl[4];
    if constexpr (WS) {
      const size_t rb = (((size_t)(2 + vsel) * 8 + b) * 128 + hd * NR + lm) * 128;
#pragma unroll
      for (int ks = 0; ks < 4; ++ks) {
        wbh[ks] = *(const u32x4*)&whi[rb + ks * 32 + lk * 8];
        wbl[ks] = *(const u32x4*)&wlo[rb + ks * 32 + lk * 8];
      }
    } else {
      const float* wrow = (vsel ? wv : wu) + ((size_t)b * ND + hd * NR + lm) * ND;
#pragma unroll
      for (int ks = 0; ks < 4; ++ks) {
        float4 x0 = *(const float4*)(wrow + ks * 32 + lk * 8);
        float4 x1 = *(const float4*)(wrow + ks * 32 + lk * 8 + 4);
        uint2 r0 = split2(x0.x, x0.y), r1 = split2(x0.z, x0.w);
        uint2 r2 = split2(x1.x, x1.y), r3 = split2(x1.z, x1.w);
        wbh[ks] = u32x4{r0.x, r1.x, r2.x, r3.x};
        wbl[ks] = u32x4{r0.y, r1.y, r2.y, r3.y};
      }
    }
    f32x4 pacc[4] = {zf, zf, zf, zf};
#pragma unroll
    for (int ks = 0; ks < 4; ++ks) {
#pragma unroll
      for (int mm = 0; mm < 4; ++mm) {
        int row = (mset + mm) * 16 + lm;
        short8 ah = *(const short8*)&zhi[row * TS_Z + ks * 32 + lk * 8];
        short8 al = *(const short8*)&zlo[row * TS_Z + ks * 32 + lk * 8];
        pacc[mm] = MFMA(ah, s8(wbh[ks]), pacc[mm]);
        pacc[mm] = MFMA(ah, s8(wbl[ks]), pacc[mm]);
        pacc[mm] = MFMA(al, s8(wbh[ks]), pacc[mm]);
      }
    }
#pragma unroll
    for (int mm = 0; mm < 4; ++mm) {
#pragma unroll
      for (int r = 0; r < 4; ++r) {
        float v = pacc[mm][r] * qsc;
        int row = (mset + mm) * 16 + lk * 4 + r, col = nt * 16 + lm;
        short hh = bfh(v);
        qhi[row * TS_Q + col] = hh;
        qlo[row * TS_Q + col] = bfh(v - bff(hh));
      }
    }
    __syncthreads();

    // ---- logits + softmax over d'; wave w owns m-tile w ----
#pragma unroll
    for (int hh = 0; hh < 2; ++hh) {
      short8 ah = z8, al = z8;
      if (l < 32) {
        ah = *(const short8*)&qhi[(w * 16 + lm) * TS_Q + 32 * hh + lk * 8];
        al = *(const short8*)&qlo[(w * 16 + lm) * TS_Q + 32 * hh + lk * 8];
      }
      f32x4 s[8];
#pragma unroll
      for (int qt = 0; qt < 8; ++qt) {
        s[qt] = zf;
        short8 bh = z8, bl = z8;
        if (l < 32) {
          bh = *(const short8*)&qhi[(qt * 16 + lm) * TS_Q + 32 * hh + 16 + lk * 8];
          bl = *(const short8*)&qlo[(qt * 16 + lm) * TS_Q + 32 * hh + 16 + lk * 8];
        }
        s[qt] = MFMA(ah, bh, s[qt]);
        s[qt] = MFMA(ah, bl, s[qt]);
        s[qt] = MFMA(al, bh, s[qt]);
      }
#pragma unroll
      for (int r = 0; r < 4; ++r) {
        float mx = s[0][r];
#pragma unroll
        for (int qt = 1; qt < 8; ++qt) mx = fmaxf(mx, s[qt][r]);
        mx = fmaxf(mx, __shfl_xor(mx, 1));
        mx = fmaxf(mx, __shfl_xor(mx, 2));
        mx = fmaxf(mx, __shfl_xor(mx, 4));
        mx = fmaxf(mx, __shfl_xor(mx, 8));
        float e[8], sum = 0.f;
#pragma unroll
        for (int qt = 0; qt < 8; ++qt) { e[qt] = __expf(s[qt][r] - mx); sum += e[qt]; }
        sum += __shfl_xor(sum, 1);
        sum += __shfl_xor(sum, 2);
        sum += __shfl_xor(sum, 4);
        sum += __shfl_xor(sum, 8);
        float inv = 1.0f / sum;
#pragma unroll
        for (int qt = 0; qt < 8; ++qt) aacc[r][qt] += e[qt] * inv;
      }
    }
    __syncthreads();
  }

  // ---- elementwise finish: m_c = (abar/8) * z, exact fp32 z from global ----
#pragma unroll
  for (int r = 0; r < 4; ++r) {
    int cc = w * 16 + lk * 4 + r;
    const float* zrow = qz + ((size_t)(b * NC + cc) * NP + p) * ND;
    float* orow = out + ((size_t)(b * NC + cc) * NP + p) * ND;
#pragma unroll
    for (int qt = 0; qt < 8; ++qt) {
      int d = qt * 16 + lm;
      orow[d] = 0.125f * aacc[r][qt] * zrow[d];
    }
  }
}

extern "C" void kernel_launch(void* const* d_in, const int* in_sizes, int n_in,
                              void* d_out, int out_size, void* d_ws, size_t ws_size,
                              hipStream_t stream) {
  const float* qz  = (const float*)d_in[0];
  const float* tuw = (const float*)d_in[1];
  const float* tvw = (const float*)d_in[2];
  const float* cuw = (const float*)d_in[3];
  const float* cvw = (const float*)d_in[4];
  float* out_t = (float*)d_out;
  float* out_c = out_t + (size_t)NB * NC * NP * ND;

  if (ws_size >= W_NEED) {
    short* whi = (short*)d_ws;
    short* wlo = whi + W_ELEMS;
    prep_w<<<256, 256, 0, stream>>>(tuw, tvw, cuw, cvw, whi, wlo);
    tmsg_kernel<1><<<dim3(NC, NB), 512, 0, stream>>>(qz, tuw, tvw, whi, wlo, out_t);
    cmsg_kernel<1><<<dim3(NP, NB), 512, 0, stream>>>(qz, cuw, cvw, whi, wlo, out_c);
  } else {
    tmsg_kernel<0><<<dim3(NC, NB), 512, 0, stream>>>(qz, tuw, tvw, nullptr, nullptr, out_t);
    cmsg_kernel<0><<<dim3(NP, NB), 512, 0, stream>>>(qz, cuw, cvw, nullptr, nullptr, out_c);
  }
}